// Round 5
// baseline (1499.732 us; speedup 1.0000x reference)
//
#include <hip/hip_runtime.h>
#include <math.h>

#define NBOND 7
#define NLAY 8
#define NTYPE 6
#define NNODES 16384   // B*N = 128*128
#define PX 136         // LDS pitch in halves (272 B, 16B-aligned; 68 dw % 32 = 4 -> conflict-clean)

typedef _Float16 half8 __attribute__((ext_vector_type(8)));
typedef _Float16 half4 __attribute__((ext_vector_type(4)));
typedef float floatx16 __attribute__((ext_vector_type(16)));

__device__ __forceinline__ float sig_(float x) { return 1.0f / (1.0f + __expf(-x)); }
// D-layout for 32x32 MFMA: col = lane&31, row = (reg&3) + 8*(reg>>2) + 4*(lane>>5)
__device__ __forceinline__ int drow_(int reg, int hi) { return (reg & 3) + 8 * (reg >> 2) + 4 * hi; }

__device__ __forceinline__ _Float16 hi_(float v) { return (_Float16)v; }
__device__ __forceinline__ _Float16 lo_(float v) { return (_Float16)(v - (float)(_Float16)v); }

// ---------------------------------------------------------------- setup
__global__ void setup_kernel(const float* __restrict__ h, float* __restrict__ hT,
                             int* __restrict__ counts, int* __restrict__ bucket)
{
    int gid = blockIdx.x * 256 + threadIdx.x;
    int node = gid >> 7, d = gid & 127;
    hT[gid] = (d < 75) ? h[node * 75 + d] : 0.0f;
    if (gid < NNODES) {
        float a = h[gid * 75];
        int tt = 5;
        if      (a == 6.0f) tt = 0;
        else if (a == 7.0f) tt = 1;
        else if (a == 8.0f) tt = 2;
        else if (a == 9.0f) tt = 3;
        else if (a == 0.0f) tt = 4;
        int slot = atomicAdd(&counts[tt], 1);
        bucket[tt * NNODES + slot] = gid;
    }
}

// ---------------------------------------------------------------- weight packing (fp32 -> split fp16 hi/lo planes)
// msgW: [(kb*8+l)][c 0..15][plane hi/lo][e 0..127][j 0..7]  (j along input dim d)
__global__ void pack_msg_kernel(const float* __restrict__ msgW, _Float16* __restrict__ Wp)
{
    int idx = blockIdx.x * 256 + threadIdx.x;
    if (idx >= NBOND * NLAY * 16 * 128) return;
    int e  = idx & 127;
    int c  = (idx >> 7) & 15;
    int kl = idx >> 11;
    const float* src = msgW + ((size_t)kl * 128 + e) * 128 + c * 8;
    float4 u = *(const float4*)src;
    float4 v = *(const float4*)(src + 4);
    float av[8] = {u.x, u.y, u.z, u.w, v.x, v.y, v.z, v.w};
    half8 hh, ll;
    #pragma unroll
    for (int j = 0; j < 8; ++j) { hh[j] = hi_(av[j]); ll[j] = lo_(av[j]); }
    _Float16* dst = Wp + ((size_t)kl * 16 + c) * 2048;
    *(half8*)(dst + e * 8)        = hh;
    *(half8*)(dst + 1024 + e * 8) = ll;
}

// GRU: [(vt*2+mat)][c 0..15][plane hi/lo][col 0..383][j 0..7]
__global__ void pack_gru_kernel(const float* __restrict__ Wih, const float* __restrict__ Whh,
                                _Float16* __restrict__ Wp)
{
    int idx = blockIdx.x * 256 + threadIdx.x;
    if (idx >= 2 * NTYPE * 2 * 16 * 384) return;
    int col = idx % 384;
    int c   = (idx / 384) & 15;
    int vm  = idx / 6144;       // (vt*2 + mat), vt = v*6+tt
    int mat = vm & 1;
    int vt  = vm >> 1;
    const float* src = (mat ? Whh : Wih) + ((size_t)vt * 384 + col) * 128 + c * 8;
    float4 u = *(const float4*)src;
    float4 v = *(const float4*)(src + 4);
    float av[8] = {u.x, u.y, u.z, u.w, v.x, v.y, v.z, v.w};
    half8 hh, ll;
    #pragma unroll
    for (int j = 0; j < 8; ++j) { hh[j] = hi_(av[j]); ll[j] = lo_(av[j]); }
    _Float16* dst = Wp + (size_t)vm * 98304 + (size_t)c * 6144;
    *(half8*)(dst + col * 8)        = hh;
    *(half8*)(dst + 3072 + col * 8) = ll;
}

// ---------------------------------------------------------------- MLP + aggregation (split-fp16 MFMA)
// One block per (kb, b): 128 nodes resident in LDS through 8 layers.
// 512 threads / 8 waves, 68 KB LDS -> 2 blocks/CU, 4 waves/SIMD.
// MLP: wave w = (col-tile w&3) x (row-half w>>2). The wave's WHOLE layer weight
// slice (16 x half8 = 64 VGPRs) is register-resident; the NEXT layer's 16 loads
// are issued right after the last W use and stay in flight ACROSS the
// inter-layer barriers: raw s_barrier (no vmcnt drain, unlike __syncthreads) +
// explicit lgkmcnt(0) only where LDS writes must become visible.
// Layer-7 tail issues the 16 HBM g-tile loads instead (consumed in agg phase).
__global__ __launch_bounds__(512, 4) void mlp_agg_mfma(
    const float* __restrict__ hin, const _Float16* __restrict__ Wp,
    const float* __restrict__ gmat, float* __restrict__ m_non, float* __restrict__ m_uni)
{
    __shared__ _Float16 Xhi[128 * PX];
    __shared__ _Float16 Xlo[128 * PX];

    const int t = threadIdx.x;
    const int kb = blockIdx.x, b = blockIdx.y;
    const int wave = t >> 6, lane = t & 63, lo = lane & 31, hi = lane >> 5;
    const int ctw = wave & 3, rh = wave >> 2;   // MLP: col-tile, row-half
    const int wcol = ctw * 32 + lo;             // MLP-phase output column
    const int rtw = wave & 3, ch = wave >> 2;   // agg: row-tile, col-half
    const int aggrow = rtw * 32 + lo;
    const float* grow = gmat + (size_t)(b * NBOND + kb) * 16384;

    half8 Wh[8], Wl[8];
    float4 greg[16];
    floatx16 acc[2];

    // issue layer-0 weight loads first (latency overlaps the X staging below)
    {
        const _Float16* wb0 = Wp + ((size_t)(kb * NLAY) * 16) * 2048;
        #pragma unroll
        for (int kk = 0; kk < 8; ++kk) {
            const _Float16* bp = wb0 + (size_t)(kk * 2 + hi) * 2048;
            Wh[kk] = *(const half8*)(bp + wcol * 8);
            Wl[kk] = *(const half8*)(bp + 1024 + wcol * 8);
        }
    }
    __builtin_amdgcn_sched_barrier(0);

    // stage layer-0 activations (fp32 -> hi/lo fp16)
    for (int q = t; q < 128 * 32; q += 512) {
        int r = q >> 5, c4 = q & 31;
        float4 v = *(const float4*)(hin + ((size_t)(b * 128 + r)) * 128 + c4 * 4);
        half4 hh, ll;
        hh[0] = hi_(v.x); ll[0] = lo_(v.x);
        hh[1] = hi_(v.y); ll[1] = lo_(v.y);
        hh[2] = hi_(v.z); ll[2] = lo_(v.z);
        hh[3] = hi_(v.w); ll[3] = lo_(v.w);
        *(half4*)(Xhi + r * PX + c4 * 4) = hh;
        *(half4*)(Xlo + r * PX + c4 * 4) = ll;
    }
    __syncthreads();

    #pragma unroll 1
    for (int l = 0; l < NLAY; ++l) {
        #pragma unroll
        for (int r2 = 0; r2 < 2; ++r2) acc[r2] = (floatx16)0.0f;

        #pragma unroll
        for (int kk = 0; kk < 8; ++kk) {
            #pragma unroll
            for (int r2 = 0; r2 < 2; ++r2) {
                int rrow = (rh * 2 + r2) * 32 + lo;
                half8 a_h = *(const half8*)(Xhi + rrow * PX + kk * 16 + hi * 8);
                half8 a_l = *(const half8*)(Xlo + rrow * PX + kk * 16 + hi * 8);
                acc[r2] = __builtin_amdgcn_mfma_f32_32x32x16_f16(a_h, Wh[kk], acc[r2], 0, 0, 0);
                acc[r2] = __builtin_amdgcn_mfma_f32_32x32x16_f16(a_h, Wl[kk], acc[r2], 0, 0, 0);
                acc[r2] = __builtin_amdgcn_mfma_f32_32x32x16_f16(a_l, Wh[kk], acc[r2], 0, 0, 0);
            }
        }

        // W regs dead now: issue next layer's weight loads (or the agg g-tile)
        if (l < NLAY - 1) {
            const _Float16* wbn = Wp + ((size_t)(kb * NLAY + l + 1) * 16) * 2048;
            #pragma unroll
            for (int kk = 0; kk < 8; ++kk) {
                const _Float16* bp = wbn + (size_t)(kk * 2 + hi) * 2048;
                Wh[kk] = *(const half8*)(bp + wcol * 8);
                Wl[kk] = *(const half8*)(bp + 1024 + wcol * 8);
            }
        } else {
            #pragma unroll
            for (int k2 = 0; k2 < 8; ++k2) {
                const float* gp = grow + (size_t)aggrow * 128 + k2 * 16 + hi * 8;
                greg[k2 * 2]     = *(const float4*)gp;
                greg[k2 * 2 + 1] = *(const float4*)(gp + 4);
            }
        }
        __builtin_amdgcn_sched_barrier(0);

        // barrier 1: all waves' X reads for layer l done. Reads are already
        // consumed by MFMAs (lgkmcnt drained at use) -> raw s_barrier, no
        // vmcnt drain: the W/g prefetch stays in flight.
        asm volatile("" ::: "memory");
        __builtin_amdgcn_s_barrier();

        if (l < NLAY - 1) {
            // writeback: fixed column wcol, rows (rh*2+r2)*32+drow
            #pragma unroll
            for (int r2 = 0; r2 < 2; ++r2)
                #pragma unroll
                for (int reg = 0; reg < 16; ++reg) {
                    int n = (rh * 2 + r2) * 32 + drow_(reg, hi);
                    float vv = fmaxf(acc[r2][reg], 0.0f);
                    Xhi[n * PX + wcol] = hi_(vv);
                    Xlo[n * PX + wcol] = lo_(vv);
                }
        } else {
            // final layer: Xt[e][m]; lane's fixed dim IS e=wcol -> contiguous half4 in m
            #pragma unroll
            for (int r2 = 0; r2 < 2; ++r2)
                #pragma unroll
                for (int s = 0; s < 4; ++s) {
                    int m0 = (rh * 2 + r2) * 32 + 8 * s + 4 * hi;
                    half4 hh, ll;
                    #pragma unroll
                    for (int j = 0; j < 4; ++j) {
                        float vv = acc[r2][4 * s + j];
                        hh[j] = hi_(vv); ll[j] = lo_(vv);
                    }
                    *(half4*)(Xhi + wcol * PX + m0) = hh;
                    *(half4*)(Xlo + wcol * PX + m0) = ll;
                }
        }

        // barrier 2: LDS writes must be visible -> lgkmcnt(0) only (no vmcnt).
        asm volatile("s_waitcnt lgkmcnt(0)" ::: "memory");
        __builtin_amdgcn_s_barrier();
        asm volatile("" ::: "memory");
        __builtin_amdgcn_sched_barrier(0);
    }

    // ---- aggregation: m[n][d] = sum_m g[b,kb,n,m]*xb[m][d]; A = greg (regs), B = Xt ----
    #pragma unroll
    for (int c2 = 0; c2 < 2; ++c2) acc[c2] = (floatx16)0.0f;

    #pragma unroll
    for (int kk = 0; kk < 8; ++kk) {
        float4 u = greg[kk * 2], v2 = greg[kk * 2 + 1];
        float av[8] = {u.x, u.y, u.z, u.w, v2.x, v2.y, v2.z, v2.w};
        half8 a_h, a_l;
        #pragma unroll
        for (int j = 0; j < 8; ++j) { a_h[j] = hi_(av[j]); a_l[j] = lo_(av[j]); }
        #pragma unroll
        for (int c2 = 0; c2 < 2; ++c2) {
            int ct = ch * 2 + c2;
            half8 b_h = *(const half8*)(Xhi + (ct * 32 + lo) * PX + kk * 16 + hi * 8);
            half8 b_l = *(const half8*)(Xlo + (ct * 32 + lo) * PX + kk * 16 + hi * 8);
            acc[c2] = __builtin_amdgcn_mfma_f32_32x32x16_f16(a_h, b_h, acc[c2], 0, 0, 0);
            acc[c2] = __builtin_amdgcn_mfma_f32_32x32x16_f16(a_h, b_l, acc[c2], 0, 0, 0);
            acc[c2] = __builtin_amdgcn_mfma_f32_32x32x16_f16(a_l, b_h, acc[c2], 0, 0, 0);
        }
    }

    if (kb == NBOND - 1) {
        #pragma unroll
        for (int c2 = 0; c2 < 2; ++c2)
            #pragma unroll
            for (int reg = 0; reg < 16; ++reg) {
                int n = rtw * 32 + drow_(reg, hi);
                m_uni[((size_t)(b * 128 + n)) * 128 + (ch * 2 + c2) * 32 + lo] = acc[c2][reg];
            }
    } else {
        #pragma unroll
        for (int c2 = 0; c2 < 2; ++c2)
            #pragma unroll
            for (int reg = 0; reg < 16; ++reg) {
                int n = rtw * 32 + drow_(reg, hi);
                atomicAdd(m_non + ((size_t)(b * 128 + n)) * 128 + (ch * 2 + c2) * 32 + lo,
                          acc[c2][reg]);
            }
    }
}

// ---------------------------------------------------------------- grouped GRU (split-fp16 MFMA)
// One block = 32 gathered nodes of one type, BOTH GRU variants (v-loop, M
// restaged per v). LDS 35 KB -> up to 4 blocks/CU. Block owns its 32 nodes
// exclusively -> in-place update of hT: v=0 stores, v=1 read-add-stores.
// No atomics, no ping-pong, no hout memset.
__global__ __launch_bounds__(256, 3) void gru_mfma(
    float* __restrict__ hT,
    const float* __restrict__ m_non, const float* __restrict__ m_uni,
    const int* __restrict__ counts, const int* __restrict__ bucket,
    const _Float16* __restrict__ Wp, const float* __restrict__ bihp, const float* __restrict__ bhhp)
{
    __shared__ _Float16 Xh[32 * PX], Xl[32 * PX], Mh[32 * PX], Ml[32 * PX];
    __shared__ int bl[32];

    const int t = threadIdx.x, tt = blockIdx.y, rtile = blockIdx.z;
    const int cnt  = counts[tt];
    const int base = blockIdx.x * 64 + rtile * 32;
    if (base >= cnt) return;
    const int nn = min(32, cnt - base);
    if (t < 32) bl[t] = (t < nn) ? bucket[tt * NNODES + base + t] : -1;
    __syncthreads();

    // stage X once (gathered h rows, split fp16, zero-fill inactive)
    for (int q = t; q < 32 * 32; q += 256) {
        int r = q >> 5, c4 = q & 31;
        float4 xv = make_float4(0.f, 0.f, 0.f, 0.f);
        int node = bl[r];
        if (node >= 0) xv = *(const float4*)(hT + (size_t)node * 128 + c4 * 4);
        half4 hh, ll;
        hh[0] = hi_(xv.x); ll[0] = lo_(xv.x);
        hh[1] = hi_(xv.y); ll[1] = lo_(xv.y);
        hh[2] = hi_(xv.z); ll[2] = lo_(xv.z);
        hh[3] = hi_(xv.w); ll[3] = lo_(xv.w);
        *(half4*)(Xh + r * PX + c4 * 4) = hh;
        *(half4*)(Xl + r * PX + c4 * 4) = ll;
    }

    const int wave = t >> 6, lane = t & 63, lo = lane & 31, hi = lane >> 5;
    const int d = wave * 32 + lo;

    #pragma unroll 1
    for (int v = 0; v < 2; ++v) {
        const float* msrc = v ? m_uni : m_non;
        __syncthreads();   // v=0: X-stage commit; v=1: prior M readers done
        for (int q = t; q < 32 * 32; q += 256) {
            int r = q >> 5, c4 = q & 31;
            float4 mv = make_float4(0.f, 0.f, 0.f, 0.f);
            int node = bl[r];
            if (node >= 0) mv = *(const float4*)(msrc + (size_t)node * 128 + c4 * 4);
            half4 hh, ll;
            hh[0] = hi_(mv.x); ll[0] = lo_(mv.x);
            hh[1] = hi_(mv.y); ll[1] = lo_(mv.y);
            hh[2] = hi_(mv.z); ll[2] = lo_(mv.z);
            hh[3] = hi_(mv.w); ll[3] = lo_(mv.w);
            *(half4*)(Mh + r * PX + c4 * 4) = hh;
            *(half4*)(Ml + r * PX + c4 * 4) = ll;
        }
        __syncthreads();

        const int vt = v * NTYPE + tt;
        const _Float16* pih = Wp + (size_t)(vt * 2 + 0) * 98304;
        const _Float16* phh = Wp + (size_t)(vt * 2 + 1) * 98304;

        floatx16 ar = (floatx16)0.0f, az = (floatx16)0.0f;
        floatx16 ax = (floatx16)0.0f, ah = (floatx16)0.0f;

        #pragma unroll 2
        for (int kk = 0; kk < 8; ++kk) {
            int koff = kk * 16 + hi * 8;
            half8 xh = *(const half8*)(Xh + lo * PX + koff);
            half8 xl = *(const half8*)(Xl + lo * PX + koff);
            half8 mh = *(const half8*)(Mh + lo * PX + koff);
            half8 ml = *(const half8*)(Ml + lo * PX + koff);
            const _Float16* ci = pih + (size_t)(kk * 2 + hi) * 6144;
            const _Float16* ch = phh + (size_t)(kk * 2 + hi) * 6144;
            half8 birh = *(const half8*)(ci + (0   + d) * 8);
            half8 birl = *(const half8*)(ci + 3072 + (0   + d) * 8);
            half8 bizh = *(const half8*)(ci + (128 + d) * 8);
            half8 bizl = *(const half8*)(ci + 3072 + (128 + d) * 8);
            half8 binh = *(const half8*)(ci + (256 + d) * 8);
            half8 binl = *(const half8*)(ci + 3072 + (256 + d) * 8);
            half8 bhrh = *(const half8*)(ch + (0   + d) * 8);
            half8 bhrl = *(const half8*)(ch + 3072 + (0   + d) * 8);
            half8 bhzh = *(const half8*)(ch + (128 + d) * 8);
            half8 bhzl = *(const half8*)(ch + 3072 + (128 + d) * 8);
            half8 bhnh = *(const half8*)(ch + (256 + d) * 8);
            half8 bhnl = *(const half8*)(ch + 3072 + (256 + d) * 8);

            ar = __builtin_amdgcn_mfma_f32_32x32x16_f16(xh, birh, ar, 0, 0, 0);
            ar = __builtin_amdgcn_mfma_f32_32x32x16_f16(xh, birl, ar, 0, 0, 0);
            ar = __builtin_amdgcn_mfma_f32_32x32x16_f16(xl, birh, ar, 0, 0, 0);
            ar = __builtin_amdgcn_mfma_f32_32x32x16_f16(mh, bhrh, ar, 0, 0, 0);
            ar = __builtin_amdgcn_mfma_f32_32x32x16_f16(mh, bhrl, ar, 0, 0, 0);
            ar = __builtin_amdgcn_mfma_f32_32x32x16_f16(ml, bhrh, ar, 0, 0, 0);

            az = __builtin_amdgcn_mfma_f32_32x32x16_f16(xh, bizh, az, 0, 0, 0);
            az = __builtin_amdgcn_mfma_f32_32x32x16_f16(xh, bizl, az, 0, 0, 0);
            az = __builtin_amdgcn_mfma_f32_32x32x16_f16(xl, bizh, az, 0, 0, 0);
            az = __builtin_amdgcn_mfma_f32_32x32x16_f16(mh, bhzh, az, 0, 0, 0);
            az = __builtin_amdgcn_mfma_f32_32x32x16_f16(mh, bhzl, az, 0, 0, 0);
            az = __builtin_amdgcn_mfma_f32_32x32x16_f16(ml, bhzh, az, 0, 0, 0);

            ax = __builtin_amdgcn_mfma_f32_32x32x16_f16(xh, binh, ax, 0, 0, 0);
            ax = __builtin_amdgcn_mfma_f32_32x32x16_f16(xh, binl, ax, 0, 0, 0);
            ax = __builtin_amdgcn_mfma_f32_32x32x16_f16(xl, binh, ax, 0, 0, 0);
            ah = __builtin_amdgcn_mfma_f32_32x32x16_f16(mh, bhnh, ah, 0, 0, 0);
            ah = __builtin_amdgcn_mfma_f32_32x32x16_f16(mh, bhnl, ah, 0, 0, 0);
            ah = __builtin_amdgcn_mfma_f32_32x32x16_f16(ml, bhnh, ah, 0, 0, 0);
        }

        const float* bi = bihp + (size_t)vt * 384;
        const float* bh = bhhp + (size_t)vt * 384;
        float b_r  = bi[d] + bh[d];
        float b_z  = bi[128 + d] + bh[128 + d];
        float b_in = bi[256 + d];
        float b_hn = bh[256 + d];
        #pragma unroll
        for (int reg = 0; reg < 16; ++reg) {
            int n = drow_(reg, hi);
            int node = bl[n];
            if (node < 0) continue;
            float r  = sig_(ar[reg] + b_r);
            float z  = sig_(az[reg] + b_z);
            float nv = tanhf(ax[reg] + b_in + r * (ah[reg] + b_hn));
            float mv = msrc[(size_t)node * 128 + d];   // fp32 m for z*m
            float val = (1.0f - z) * nv + z * mv;
            if (v == 0) hT[(size_t)node * 128 + d] = val;                       // overwrite old h
            else        hT[(size_t)node * 128 + d] += val;                      // block owns node
        }
    }
}

// ---------------------------------------------------------------- launch
extern "C" void kernel_launch(void* const* d_in, const int* in_sizes, int n_in,
                              void* d_out, int out_size, void* d_ws, size_t ws_size,
                              hipStream_t stream) {
    const float* g    = (const float*)d_in[0];
    const float* h    = (const float*)d_in[1];
    const float* msgW = (const float*)d_in[2];
    const float* Wih  = (const float*)d_in[3];
    const float* Whh  = (const float*)d_in[4];
    const float* bih  = (const float*)d_in[5];
    const float* bhh  = (const float*)d_in[6];
    float* hT = (float*)d_out;

    char* ws = (char*)d_ws;
    float* m_non = (float*)ws;                                   // 8 MB
    float* m_uni = m_non + (size_t)NNODES * 128;                 // 8 MB
    int* counts  = (int*)(ws + 2 * (size_t)NNODES * 128 * 4);
    int* bucket  = counts + 8;                                   // [6][16384]
    _Float16* WpM = (_Float16*)(bucket + NTYPE * NNODES);        // 1,835,008 halves (3.67 MB)
    _Float16* WpG = WpM + (size_t)NBOND * NLAY * 16 * 2048;      // 2,359,296 halves (4.72 MB)

    (void)hipMemsetAsync(counts, 0, 8 * sizeof(int), stream);
    setup_kernel<<<NNODES * 128 / 256, 256, 0, stream>>>(h, hT, counts, bucket);
    pack_msg_kernel<<<(NBOND * NLAY * 16 * 128 + 255) / 256, 256, 0, stream>>>(msgW, WpM);
    pack_gru_kernel<<<(2 * NTYPE * 2 * 16 * 384 + 255) / 256, 256, 0, stream>>>(Wih, Whh, WpG);

    for (int pass = 0; pass < 3; ++pass) {
        (void)hipMemsetAsync(m_non, 0, (size_t)NNODES * 128 * 4, stream);
        mlp_agg_mfma<<<dim3(NBOND, 128), 512, 0, stream>>>(hT, WpM, g, m_non, m_uni);
        gru_mfma<<<dim3(NNODES / 64, NTYPE, 2), 256, 0, stream>>>(hT, m_non, m_uni, counts, bucket,
                                                                  WpG, bih, bhh);
    }
}

// Round 6
// 880.904 us; speedup vs baseline: 1.7025x; 1.7025x over previous
//
#include <hip/hip_runtime.h>
#include <math.h>

#define NBOND 7
#define NLAY 8
#define NTYPE 6
#define NNODES 16384   // B*N = 128*128
#define PX 136         // LDS pitch in halves (272 B, 16B-aligned; 68 dw % 32 = 4 -> conflict-clean)
#define WCH 2048       // halves per weight chunk (4 KB: [hi 1024][lo 1024])

typedef _Float16 half8 __attribute__((ext_vector_type(8)));
typedef _Float16 half4 __attribute__((ext_vector_type(4)));
typedef float floatx16 __attribute__((ext_vector_type(16)));

__device__ __forceinline__ float sig_(float x) { return 1.0f / (1.0f + __expf(-x)); }
// D-layout for 32x32 MFMA: col = lane&31, row = (reg&3) + 8*(reg>>2) + 4*(lane>>5)
__device__ __forceinline__ int drow_(int reg, int hi) { return (reg & 3) + 8 * (reg >> 2) + 4 * hi; }

__device__ __forceinline__ _Float16 hi_(float v) { return (_Float16)v; }
__device__ __forceinline__ _Float16 lo_(float v) { return (_Float16)(v - (float)(_Float16)v); }

// ---------------------------------------------------------------- setup
__global__ void setup_kernel(const float* __restrict__ h, float* __restrict__ hT,
                             int* __restrict__ counts, int* __restrict__ bucket)
{
    int gid = blockIdx.x * 256 + threadIdx.x;
    int node = gid >> 7, d = gid & 127;
    hT[gid] = (d < 75) ? h[node * 75 + d] : 0.0f;
    if (gid < NNODES) {
        float a = h[gid * 75];
        int tt = 5;
        if      (a == 6.0f) tt = 0;
        else if (a == 7.0f) tt = 1;
        else if (a == 8.0f) tt = 2;
        else if (a == 9.0f) tt = 3;
        else if (a == 0.0f) tt = 4;
        int slot = atomicAdd(&counts[tt], 1);
        bucket[tt * NNODES + slot] = gid;
    }
}

// ---------------------------------------------------------------- weight packing (fp32 -> split fp16 hi/lo planes)
// msgW: [(kb*8+l)][c 0..15][plane hi/lo][e 0..127][j 0..7]  (j along input dim d)
__global__ void pack_msg_kernel(const float* __restrict__ msgW, _Float16* __restrict__ Wp)
{
    int idx = blockIdx.x * 256 + threadIdx.x;
    if (idx >= NBOND * NLAY * 16 * 128) return;
    int e  = idx & 127;
    int c  = (idx >> 7) & 15;
    int kl = idx >> 11;
    const float* src = msgW + ((size_t)kl * 128 + e) * 128 + c * 8;
    float4 u = *(const float4*)src;
    float4 v = *(const float4*)(src + 4);
    float av[8] = {u.x, u.y, u.z, u.w, v.x, v.y, v.z, v.w};
    half8 hh, ll;
    #pragma unroll
    for (int j = 0; j < 8; ++j) { hh[j] = hi_(av[j]); ll[j] = lo_(av[j]); }
    _Float16* dst = Wp + ((size_t)kl * 16 + c) * WCH;
    *(half8*)(dst + e * 8)        = hh;
    *(half8*)(dst + 1024 + e * 8) = ll;
}

// GRU: [(vt*2+mat)][c 0..15][plane hi/lo][col 0..383][j 0..7]
__global__ void pack_gru_kernel(const float* __restrict__ Wih, const float* __restrict__ Whh,
                                _Float16* __restrict__ Wp)
{
    int idx = blockIdx.x * 256 + threadIdx.x;
    if (idx >= 2 * NTYPE * 2 * 16 * 384) return;
    int col = idx % 384;
    int c   = (idx / 384) & 15;
    int vm  = idx / 6144;       // (vt*2 + mat), vt = v*6+tt
    int mat = vm & 1;
    int vt  = vm >> 1;
    const float* src = (mat ? Whh : Wih) + ((size_t)vt * 384 + col) * 128 + c * 8;
    float4 u = *(const float4*)src;
    float4 v = *(const float4*)(src + 4);
    float av[8] = {u.x, u.y, u.z, u.w, v.x, v.y, v.z, v.w};
    half8 hh, ll;
    #pragma unroll
    for (int j = 0; j < 8; ++j) { hh[j] = hi_(av[j]); ll[j] = lo_(av[j]); }
    _Float16* dst = Wp + (size_t)vm * 98304 + (size_t)c * 6144;
    *(half8*)(dst + col * 8)        = hh;
    *(half8*)(dst + 3072 + col * 8) = ll;
}

// ---------------------------------------------------------------- MLP + aggregation (split-fp16 MFMA)
// One block per (kb, b): 128 nodes resident in LDS through 8 layers.
// 512 threads / 8 waves. Weights staged through LDS via global_load_lds,
// double-buffered per HALF-LAYER (kk 0-3 / 4-7, 32 KB each): while computing
// half h from Wb[h], the next half is in flight. Raw s_barrier + counted
// s_waitcnt vmcnt(4) (never 0 in the loop) keep the staging pipeline filled
// across barriers (T3/T4). Weight reads become conflict-free ds_read_b128.
// LDS = 68 KB (X hi/lo) + 64 KB (Wb) = 132 KB -> 1 block/CU, 8 waves.
// MLP: wave w = (col-tile w&3) x (row-half w>>2). Agg: (row-tile w&3) x (col-half w>>2).
__global__ __launch_bounds__(512, 2) void mlp_agg_mfma(
    const float* __restrict__ hin, const _Float16* __restrict__ Wp,
    const float* __restrict__ gmat, float* __restrict__ m_non, float* __restrict__ m_uni)
{
    __shared__ _Float16 Xhi[128 * PX];
    __shared__ _Float16 Xlo[128 * PX];
    __shared__ _Float16 Wb[2][8 * WCH];   // two 32 KB half-layer buffers

    const int t = threadIdx.x;
    const int kb = blockIdx.x, b = blockIdx.y;
    const int wave = t >> 6, lane = t & 63, lo = lane & 31, hi = lane >> 5;
    const int ctw = wave & 3, rh = wave >> 2;   // MLP: col-tile, row-half
    const int wcol = ctw * 32 + lo;             // MLP-phase output column

    const _Float16* wlay = Wp + ((size_t)(kb * NLAY) * 16) * WCH;

    // stage half-layer hfl of layer l into Wb[hfl]: 4 x global_load_lds(16B) per thread.
    // LDS dst is wave-uniform (base + wave segment); HW scatters lane*16B.
    auto stageW = [&](int l, int hfl) {
        const _Float16* src = wlay + ((size_t)l * 16 + hfl * 8) * WCH + wave * 2048 + lane * 8;
        _Float16* dst = &Wb[hfl][wave * 2048];
        #pragma unroll
        for (int i = 0; i < 4; ++i) {
            __builtin_amdgcn_global_load_lds(
                (const __attribute__((address_space(1))) void*)(src + i * 512),
                (__attribute__((address_space(3))) void*)(dst + i * 512), 16, 0, 0);
        }
    };

    // prologue: issue L0.H0 + L0.H1 stages, then X staging (regular loads)
    stageW(0, 0);
    stageW(0, 1);

    for (int q = t; q < 128 * 32; q += 512) {
        int r = q >> 5, c4 = q & 31;
        float4 v = *(const float4*)(hin + ((size_t)(b * 128 + r)) * 128 + c4 * 4);
        half4 hh, ll;
        hh[0] = hi_(v.x); ll[0] = lo_(v.x);
        hh[1] = hi_(v.y); ll[1] = lo_(v.y);
        hh[2] = hi_(v.z); ll[2] = lo_(v.z);
        hh[3] = hi_(v.w); ll[3] = lo_(v.w);
        *(half4*)(Xhi + r * PX + c4 * 4) = hh;
        *(half4*)(Xlo + r * PX + c4 * 4) = ll;
    }
    __syncthreads();   // drains vmcnt(0): X + both L0 halves landed. Fine once.

    floatx16 acc[2];

    #pragma unroll 1
    for (int l = 0; l < NLAY; ++l) {
        #pragma unroll
        for (int r2 = 0; r2 < 2; ++r2) acc[r2] = (floatx16)0.0f;

        // ---- half 0: kk = 0..3 from Wb[0] ----
        #pragma unroll
        for (int kk = 0; kk < 4; ++kk) {
            const _Float16* wp = &Wb[0][(kk * 2 + hi) * WCH];
            half8 b_h = *(const half8*)(wp + wcol * 8);
            half8 b_l = *(const half8*)(wp + 1024 + wcol * 8);
            #pragma unroll
            for (int r2 = 0; r2 < 2; ++r2) {
                int rrow = (rh * 2 + r2) * 32 + lo;
                half8 a_h = *(const half8*)(Xhi + rrow * PX + kk * 16 + hi * 8);
                half8 a_l = *(const half8*)(Xlo + rrow * PX + kk * 16 + hi * 8);
                acc[r2] = __builtin_amdgcn_mfma_f32_32x32x16_f16(a_h, b_h, acc[r2], 0, 0, 0);
                acc[r2] = __builtin_amdgcn_mfma_f32_32x32x16_f16(a_h, b_l, acc[r2], 0, 0, 0);
                acc[r2] = __builtin_amdgcn_mfma_f32_32x32x16_f16(a_l, b_h, acc[r2], 0, 0, 0);
            }
        }
        asm volatile("" ::: "memory");
        __builtin_amdgcn_s_barrier();            // B: all waves done reading Wb[0]

        if (l < NLAY - 1) {
            stageW(l + 1, 0);                    // C: refill Wb[0] (4 loads in flight)
            asm volatile("s_waitcnt vmcnt(4)" ::: "memory");   // D: L_l.H1 landed
        } else {
            asm volatile("s_waitcnt vmcnt(0)" ::: "memory");   // last layer: drain H1
        }
        __builtin_amdgcn_sched_barrier(0);
        __builtin_amdgcn_s_barrier();            // E: everyone's H1 visible

        // ---- half 1: kk = 4..7 from Wb[1] ----
        #pragma unroll
        for (int kk = 4; kk < 8; ++kk) {
            const _Float16* wp = &Wb[1][((kk - 4) * 2 + hi) * WCH];
            half8 b_h = *(const half8*)(wp + wcol * 8);
            half8 b_l = *(const half8*)(wp + 1024 + wcol * 8);
            #pragma unroll
            for (int r2 = 0; r2 < 2; ++r2) {
                int rrow = (rh * 2 + r2) * 32 + lo;
                half8 a_h = *(const half8*)(Xhi + rrow * PX + kk * 16 + hi * 8);
                half8 a_l = *(const half8*)(Xlo + rrow * PX + kk * 16 + hi * 8);
                acc[r2] = __builtin_amdgcn_mfma_f32_32x32x16_f16(a_h, b_h, acc[r2], 0, 0, 0);
                acc[r2] = __builtin_amdgcn_mfma_f32_32x32x16_f16(a_h, b_l, acc[r2], 0, 0, 0);
                acc[r2] = __builtin_amdgcn_mfma_f32_32x32x16_f16(a_l, b_h, acc[r2], 0, 0, 0);
            }
        }
        asm volatile("" ::: "memory");
        __builtin_amdgcn_s_barrier();            // G: Wb[1] reads + all X reads done

        if (l < NLAY - 1) stageW(l + 1, 1);      // H: refill Wb[1]

        if (l < NLAY - 1) {
            // writeback: fixed column wcol, rows (rh*2+r2)*32+drow
            #pragma unroll
            for (int r2 = 0; r2 < 2; ++r2)
                #pragma unroll
                for (int reg = 0; reg < 16; ++reg) {
                    int n = (rh * 2 + r2) * 32 + drow_(reg, hi);
                    float vv = fmaxf(acc[r2][reg], 0.0f);
                    Xhi[n * PX + wcol] = hi_(vv);
                    Xlo[n * PX + wcol] = lo_(vv);
                }
            // K: X writes visible (lgkm) + L_{l+1}.H0 landed (vmcnt<=4: only H's 4 newest remain)
            asm volatile("s_waitcnt vmcnt(4) lgkmcnt(0)" ::: "memory");
        } else {
            // final layer: Xt[e][m]; lane's fixed dim IS e=wcol -> contiguous half4 in m
            #pragma unroll
            for (int r2 = 0; r2 < 2; ++r2)
                #pragma unroll
                for (int s = 0; s < 4; ++s) {
                    int m0 = (rh * 2 + r2) * 32 + 8 * s + 4 * hi;
                    half4 hh, ll;
                    #pragma unroll
                    for (int j = 0; j < 4; ++j) {
                        float vv = acc[r2][4 * s + j];
                        hh[j] = hi_(vv); ll[j] = lo_(vv);
                    }
                    *(half4*)(Xhi + wcol * PX + m0) = hh;
                    *(half4*)(Xlo + wcol * PX + m0) = ll;
                }
            asm volatile("s_waitcnt lgkmcnt(0)" ::: "memory");
        }
        __builtin_amdgcn_sched_barrier(0);
        __builtin_amdgcn_s_barrier();            // K
    }

    // ---- aggregation: m[n][d] = sum_m g[b,kb,n,m]*xb[m][d]; A = g (inline split), B = Xt ----
    const int rtw = wave & 3, ch = wave >> 2;
    const int row = rtw * 32 + lo;
    #pragma unroll
    for (int c2 = 0; c2 < 2; ++c2) acc[c2] = (floatx16)0.0f;
    const float* grow = gmat + (size_t)(b * NBOND + kb) * 16384;

    #pragma unroll 2
    for (int kk = 0; kk < 8; ++kk) {
        const float* gp = grow + (size_t)row * 128 + kk * 16 + hi * 8;
        float4 u = *(const float4*)gp, v2 = *(const float4*)(gp + 4);
        float av[8] = {u.x, u.y, u.z, u.w, v2.x, v2.y, v2.z, v2.w};
        half8 a_h, a_l;
        #pragma unroll
        for (int j = 0; j < 8; ++j) { a_h[j] = hi_(av[j]); a_l[j] = lo_(av[j]); }
        #pragma unroll
        for (int c2 = 0; c2 < 2; ++c2) {
            int ct = ch * 2 + c2;
            half8 b_h = *(const half8*)(Xhi + (ct * 32 + lo) * PX + kk * 16 + hi * 8);
            half8 b_l = *(const half8*)(Xlo + (ct * 32 + lo) * PX + kk * 16 + hi * 8);
            acc[c2] = __builtin_amdgcn_mfma_f32_32x32x16_f16(a_h, b_h, acc[c2], 0, 0, 0);
            acc[c2] = __builtin_amdgcn_mfma_f32_32x32x16_f16(a_h, b_l, acc[c2], 0, 0, 0);
            acc[c2] = __builtin_amdgcn_mfma_f32_32x32x16_f16(a_l, b_h, acc[c2], 0, 0, 0);
        }
    }

    if (kb == NBOND - 1) {
        #pragma unroll
        for (int c2 = 0; c2 < 2; ++c2)
            #pragma unroll
            for (int reg = 0; reg < 16; ++reg) {
                int n = rtw * 32 + drow_(reg, hi);
                m_uni[((size_t)(b * 128 + n)) * 128 + (ch * 2 + c2) * 32 + lo] = acc[c2][reg];
            }
    } else {
        #pragma unroll
        for (int c2 = 0; c2 < 2; ++c2)
            #pragma unroll
            for (int reg = 0; reg < 16; ++reg) {
                int n = rtw * 32 + drow_(reg, hi);
                atomicAdd(m_non + ((size_t)(b * 128 + n)) * 128 + (ch * 2 + c2) * 32 + lo,
                          acc[c2][reg]);
            }
    }
}

// ---------------------------------------------------------------- grouped GRU (split-fp16 MFMA)
// One block = 32 gathered nodes of one type, BOTH GRU variants (v-loop, M
// restaged per v). LDS 35 KB -> up to 4 blocks/CU. Block owns its 32 nodes
// exclusively -> in-place update of hT: v=0 stores, v=1 read-add-stores.
// No atomics, no ping-pong, no hout memset.
__global__ __launch_bounds__(256, 3) void gru_mfma(
    float* __restrict__ hT,
    const float* __restrict__ m_non, const float* __restrict__ m_uni,
    const int* __restrict__ counts, const int* __restrict__ bucket,
    const _Float16* __restrict__ Wp, const float* __restrict__ bihp, const float* __restrict__ bhhp)
{
    __shared__ _Float16 Xh[32 * PX], Xl[32 * PX], Mh[32 * PX], Ml[32 * PX];
    __shared__ int bl[32];

    const int t = threadIdx.x, tt = blockIdx.y, rtile = blockIdx.z;
    const int cnt  = counts[tt];
    const int base = blockIdx.x * 64 + rtile * 32;
    if (base >= cnt) return;
    const int nn = min(32, cnt - base);
    if (t < 32) bl[t] = (t < nn) ? bucket[tt * NNODES + base + t] : -1;
    __syncthreads();

    // stage X once (gathered h rows, split fp16, zero-fill inactive)
    for (int q = t; q < 32 * 32; q += 256) {
        int r = q >> 5, c4 = q & 31;
        float4 xv = make_float4(0.f, 0.f, 0.f, 0.f);
        int node = bl[r];
        if (node >= 0) xv = *(const float4*)(hT + (size_t)node * 128 + c4 * 4);
        half4 hh, ll;
        hh[0] = hi_(xv.x); ll[0] = lo_(xv.x);
        hh[1] = hi_(xv.y); ll[1] = lo_(xv.y);
        hh[2] = hi_(xv.z); ll[2] = lo_(xv.z);
        hh[3] = hi_(xv.w); ll[3] = lo_(xv.w);
        *(half4*)(Xh + r * PX + c4 * 4) = hh;
        *(half4*)(Xl + r * PX + c4 * 4) = ll;
    }

    const int wave = t >> 6, lane = t & 63, lo = lane & 31, hi = lane >> 5;
    const int d = wave * 32 + lo;

    #pragma unroll 1
    for (int v = 0; v < 2; ++v) {
        const float* msrc = v ? m_uni : m_non;
        __syncthreads();   // v=0: X-stage commit; v=1: prior M readers done
        for (int q = t; q < 32 * 32; q += 256) {
            int r = q >> 5, c4 = q & 31;
            float4 mv = make_float4(0.f, 0.f, 0.f, 0.f);
            int node = bl[r];
            if (node >= 0) mv = *(const float4*)(msrc + (size_t)node * 128 + c4 * 4);
            half4 hh, ll;
            hh[0] = hi_(mv.x); ll[0] = lo_(mv.x);
            hh[1] = hi_(mv.y); ll[1] = lo_(mv.y);
            hh[2] = hi_(mv.z); ll[2] = lo_(mv.z);
            hh[3] = hi_(mv.w); ll[3] = lo_(mv.w);
            *(half4*)(Mh + r * PX + c4 * 4) = hh;
            *(half4*)(Ml + r * PX + c4 * 4) = ll;
        }
        __syncthreads();

        const int vt = v * NTYPE + tt;
        const _Float16* pih = Wp + (size_t)(vt * 2 + 0) * 98304;
        const _Float16* phh = Wp + (size_t)(vt * 2 + 1) * 98304;

        floatx16 ar = (floatx16)0.0f, az = (floatx16)0.0f;
        floatx16 ax = (floatx16)0.0f, ah = (floatx16)0.0f;

        #pragma unroll 2
        for (int kk = 0; kk < 8; ++kk) {
            int koff = kk * 16 + hi * 8;
            half8 xh = *(const half8*)(Xh + lo * PX + koff);
            half8 xl = *(const half8*)(Xl + lo * PX + koff);
            half8 mh = *(const half8*)(Mh + lo * PX + koff);
            half8 ml = *(const half8*)(Ml + lo * PX + koff);
            const _Float16* ci = pih + (size_t)(kk * 2 + hi) * 6144;
            const _Float16* ch = phh + (size_t)(kk * 2 + hi) * 6144;
            half8 birh = *(const half8*)(ci + (0   + d) * 8);
            half8 birl = *(const half8*)(ci + 3072 + (0   + d) * 8);
            half8 bizh = *(const half8*)(ci + (128 + d) * 8);
            half8 bizl = *(const half8*)(ci + 3072 + (128 + d) * 8);
            half8 binh = *(const half8*)(ci + (256 + d) * 8);
            half8 binl = *(const half8*)(ci + 3072 + (256 + d) * 8);
            half8 bhrh = *(const half8*)(ch + (0   + d) * 8);
            half8 bhrl = *(const half8*)(ch + 3072 + (0   + d) * 8);
            half8 bhzh = *(const half8*)(ch + (128 + d) * 8);
            half8 bhzl = *(const half8*)(ch + 3072 + (128 + d) * 8);
            half8 bhnh = *(const half8*)(ch + (256 + d) * 8);
            half8 bhnl = *(const half8*)(ch + 3072 + (256 + d) * 8);

            ar = __builtin_amdgcn_mfma_f32_32x32x16_f16(xh, birh, ar, 0, 0, 0);
            ar = __builtin_amdgcn_mfma_f32_32x32x16_f16(xh, birl, ar, 0, 0, 0);
            ar = __builtin_amdgcn_mfma_f32_32x32x16_f16(xl, birh, ar, 0, 0, 0);
            ar = __builtin_amdgcn_mfma_f32_32x32x16_f16(mh, bhrh, ar, 0, 0, 0);
            ar = __builtin_amdgcn_mfma_f32_32x32x16_f16(mh, bhrl, ar, 0, 0, 0);
            ar = __builtin_amdgcn_mfma_f32_32x32x16_f16(ml, bhrh, ar, 0, 0, 0);

            az = __builtin_amdgcn_mfma_f32_32x32x16_f16(xh, bizh, az, 0, 0, 0);
            az = __builtin_amdgcn_mfma_f32_32x32x16_f16(xh, bizl, az, 0, 0, 0);
            az = __builtin_amdgcn_mfma_f32_32x32x16_f16(xl, bizh, az, 0, 0, 0);
            az = __builtin_amdgcn_mfma_f32_32x32x16_f16(mh, bhzh, az, 0, 0, 0);
            az = __builtin_amdgcn_mfma_f32_32x32x16_f16(mh, bhzl, az, 0, 0, 0);
            az = __builtin_amdgcn_mfma_f32_32x32x16_f16(ml, bhzh, az, 0, 0, 0);

            ax = __builtin_amdgcn_mfma_f32_32x32x16_f16(xh, binh, ax, 0, 0, 0);
            ax = __builtin_amdgcn_mfma_f32_32x32x16_f16(xh, binl, ax, 0, 0, 0);
            ax = __builtin_amdgcn_mfma_f32_32x32x16_f16(xl, binh, ax, 0, 0, 0);
            ah = __builtin_amdgcn_mfma_f32_32x32x16_f16(mh, bhnh, ah, 0, 0, 0);
            ah = __builtin_amdgcn_mfma_f32_32x32x16_f16(mh, bhnl, ah, 0, 0, 0);
            ah = __builtin_amdgcn_mfma_f32_32x32x16_f16(ml, bhnh, ah, 0, 0, 0);
        }

        const float* bi = bihp + (size_t)vt * 384;
        const float* bh = bhhp + (size_t)vt * 384;
        float b_r  = bi[d] + bh[d];
        float b_z  = bi[128 + d] + bh[128 + d];
        float b_in = bi[256 + d];
        float b_hn = bh[256 + d];
        #pragma unroll
        for (int reg = 0; reg < 16; ++reg) {
            int n = drow_(reg, hi);
            int node = bl[n];
            if (node < 0) continue;
            float r  = sig_(ar[reg] + b_r);
            float z  = sig_(az[reg] + b_z);
            float nv = tanhf(ax[reg] + b_in + r * (ah[reg] + b_hn));
            float mv = msrc[(size_t)node * 128 + d];   // fp32 m for z*m
            float val = (1.0f - z) * nv + z * mv;
            if (v == 0) hT[(size_t)node * 128 + d] = val;                       // overwrite old h
            else        hT[(size_t)node * 128 + d] += val;                      // block owns node
        }
    }
}

// ---------------------------------------------------------------- launch
extern "C" void kernel_launch(void* const* d_in, const int* in_sizes, int n_in,
                              void* d_out, int out_size, void* d_ws, size_t ws_size,
                              hipStream_t stream) {
    const float* g    = (const float*)d_in[0];
    const float* h    = (const float*)d_in[1];
    const float* msgW = (const float*)d_in[2];
    const float* Wih  = (const float*)d_in[3];
    const float* Whh  = (const float*)d_in[4];
    const float* bih  = (const float*)d_in[5];
    const float* bhh  = (const float*)d_in[6];
    float* hT = (float*)d_out;

    char* ws = (char*)d_ws;
    float* m_non = (float*)ws;                                   // 8 MB
    float* m_uni = m_non + (size_t)NNODES * 128;                 // 8 MB
    int* counts  = (int*)(ws + 2 * (size_t)NNODES * 128 * 4);
    int* bucket  = counts + 8;                                   // [6][16384]
    _Float16* WpM = (_Float16*)(bucket + NTYPE * NNODES);        // 1,835,008 halves (3.67 MB)
    _Float16* WpG = WpM + (size_t)NBOND * NLAY * 16 * WCH;       // 2,359,296 halves (4.72 MB)

    (void)hipMemsetAsync(counts, 0, 8 * sizeof(int), stream);
    setup_kernel<<<NNODES * 128 / 256, 256, 0, stream>>>(h, hT, counts, bucket);
    pack_msg_kernel<<<(NBOND * NLAY * 16 * 128 + 255) / 256, 256, 0, stream>>>(msgW, WpM);
    pack_gru_kernel<<<(2 * NTYPE * 2 * 16 * 384 + 255) / 256, 256, 0, stream>>>(Wih, Whh, WpG);

    for (int pass = 0; pass < 3; ++pass) {
        (void)hipMemsetAsync(m_non, 0, (size_t)NNODES * 128 * 4, stream);
        mlp_agg_mfma<<<dim3(NBOND, 128), 512, 0, stream>>>(hT, WpM, g, m_non, m_uni);
        gru_mfma<<<dim3(NNODES / 64, NTYPE, 2), 256, 0, stream>>>(hT, m_non, m_uni, counts, bucket,
                                                                  WpG, bih, bhh);
    }
}

// Round 8
// 782.133 us; speedup vs baseline: 1.9175x; 1.1263x over previous
//
#include <hip/hip_runtime.h>
#include <math.h>

#define NBOND 7
#define NLAY 8
#define NTYPE 6
#define NNODES 16384   // B*N = 128*128
#define PX 136         // LDS pitch in halves (272 B, 16B-aligned; 68 dw % 32 = 4 -> conflict-clean)
#define NDESC 520      // 8 XCDs x 65 desc slots (>= 518 max active 32-node slices)

typedef _Float16 half8 __attribute__((ext_vector_type(8)));
typedef _Float16 half4 __attribute__((ext_vector_type(4)));
typedef float floatx16 __attribute__((ext_vector_type(16)));

__device__ __forceinline__ float sig_(float x) { return 1.0f / (1.0f + __expf(-x)); }
// D-layout for 32x32 MFMA: col = lane&31, row = (reg&3) + 8*(reg>>2) + 4*(lane>>5)
__device__ __forceinline__ int drow_(int reg, int hi) { return (reg & 3) + 8 * (reg >> 2) + 4 * hi; }

__device__ __forceinline__ _Float16 hi_(float v) { return (_Float16)v; }
__device__ __forceinline__ _Float16 lo_(float v) { return (_Float16)(v - (float)(_Float16)v); }

// ---------------------------------------------------------------- setup
__global__ void setup_kernel(const float* __restrict__ h, float* __restrict__ hT,
                             int* __restrict__ counts, int* __restrict__ bucket)
{
    int gid = blockIdx.x * 256 + threadIdx.x;
    int node = gid >> 7, d = gid & 127;
    hT[gid] = (d < 75) ? h[node * 75 + d] : 0.0f;
    if (gid < NNODES) {
        float a = h[gid * 75];
        int tt = 5;
        if      (a == 6.0f) tt = 0;
        else if (a == 7.0f) tt = 1;
        else if (a == 8.0f) tt = 2;
        else if (a == 9.0f) tt = 3;
        else if (a == 0.0f) tt = 4;
        int slot = atomicAdd(&counts[tt], 1);
        bucket[tt * NNODES + slot] = gid;
    }
}

// Build dense GRU block descriptors: desc[i] = tt | (slice<<3) for each active
// 32-node slice, -1 padding. Fixes the round-robin CU imbalance of the
// (256, 6, 2) grid (segments of 256 blocks re-hit the SAME CUs every time;
// only CUs < cnt/64 ever got work).
__global__ void build_desc_kernel(const int* __restrict__ counts, int* __restrict__ desc)
{
    if (threadIdx.x != 0 || blockIdx.x != 0) return;
    int i = 0;
    for (int tt = 0; tt < NTYPE; ++tt) {
        int nb = (counts[tt] + 31) >> 5;
        for (int s = 0; s < nb; ++s) desc[i++] = tt | (s << 3);
    }
    while (i < NDESC) desc[i++] = -1;
}

// ---------------------------------------------------------------- weight packing (fp32 -> split fp16 hi/lo planes)
// msgW: [(kb*8+l)][c 0..15][plane hi/lo][e 0..127][j 0..7]  (j along input dim d)
__global__ void pack_msg_kernel(const float* __restrict__ msgW, _Float16* __restrict__ Wp)
{
    int idx = blockIdx.x * 256 + threadIdx.x;
    if (idx >= NBOND * NLAY * 16 * 128) return;
    int e  = idx & 127;
    int c  = (idx >> 7) & 15;
    int kl = idx >> 11;
    const float* src = msgW + ((size_t)kl * 128 + e) * 128 + c * 8;
    float4 u = *(const float4*)src;
    float4 v = *(const float4*)(src + 4);
    float av[8] = {u.x, u.y, u.z, u.w, v.x, v.y, v.z, v.w};
    half8 hh, ll;
    #pragma unroll
    for (int j = 0; j < 8; ++j) { hh[j] = hi_(av[j]); ll[j] = lo_(av[j]); }
    _Float16* dst = Wp + ((size_t)kl * 16 + c) * 2048;
    *(half8*)(dst + e * 8)        = hh;
    *(half8*)(dst + 1024 + e * 8) = ll;
}

// GRU: [(vt*2+mat)][c 0..15][plane hi/lo][col 0..383][j 0..7]
__global__ void pack_gru_kernel(const float* __restrict__ Wih, const float* __restrict__ Whh,
                                _Float16* __restrict__ Wp)
{
    int idx = blockIdx.x * 256 + threadIdx.x;
    if (idx >= 2 * NTYPE * 2 * 16 * 384) return;
    int col = idx % 384;
    int c   = (idx / 384) & 15;
    int vm  = idx / 6144;       // (vt*2 + mat), vt = v*6+tt
    int mat = vm & 1;
    int vt  = vm >> 1;
    const float* src = (mat ? Whh : Wih) + ((size_t)vt * 384 + col) * 128 + c * 8;
    float4 u = *(const float4*)src;
    float4 v = *(const float4*)(src + 4);
    float av[8] = {u.x, u.y, u.z, u.w, v.x, v.y, v.z, v.w};
    half8 hh, ll;
    #pragma unroll
    for (int j = 0; j < 8; ++j) { hh[j] = hi_(av[j]); ll[j] = lo_(av[j]); }
    _Float16* dst = Wp + (size_t)vm * 98304 + (size_t)c * 6144;
    *(half8*)(dst + col * 8)        = hh;
    *(half8*)(dst + 3072 + col * 8) = ll;
}

// ---------------------------------------------------------------- MLP + aggregation (split-fp16 MFMA)
// r4 version (best measured: 152 us): one block per (kb, b), 512 threads /
// 8 waves over the 68 KB tile -> 2 blocks/CU, 4 waves/SIMD.
// MLP: wave w = (col-tile w&3) x (row-half w>>2): per kk 2 weight loads (L2)
// feed 6 MFMAs. Agg: wave w = (row-tile w&3) x (col-half w>>2).
__global__ __launch_bounds__(512, 4) void mlp_agg_mfma(
    const float* __restrict__ hin, const _Float16* __restrict__ Wp,
    const float* __restrict__ gmat, float* __restrict__ m_non, float* __restrict__ m_uni)
{
    __shared__ _Float16 Xhi[128 * PX];
    __shared__ _Float16 Xlo[128 * PX];

    const int t = threadIdx.x;
    const int kb = blockIdx.x, b = blockIdx.y;
    const int wave = t >> 6, lane = t & 63, lo = lane & 31, hi = lane >> 5;
    const int ctw = wave & 3, rh = wave >> 2;   // MLP: col-tile, row-half
    const int wcol = ctw * 32 + lo;             // MLP-phase output column

    // stage layer-0 activations (fp32 -> hi/lo fp16)
    for (int q = t; q < 128 * 32; q += 512) {
        int r = q >> 5, c4 = q & 31;
        float4 v = *(const float4*)(hin + ((size_t)(b * 128 + r)) * 128 + c4 * 4);
        half4 hh, ll;
        hh[0] = hi_(v.x); ll[0] = lo_(v.x);
        hh[1] = hi_(v.y); ll[1] = lo_(v.y);
        hh[2] = hi_(v.z); ll[2] = lo_(v.z);
        hh[3] = hi_(v.w); ll[3] = lo_(v.w);
        *(half4*)(Xhi + r * PX + c4 * 4) = hh;
        *(half4*)(Xlo + r * PX + c4 * 4) = ll;
    }
    __syncthreads();

    floatx16 acc[2];

    #pragma unroll 1
    for (int l = 0; l < NLAY; ++l) {
        #pragma unroll
        for (int r2 = 0; r2 < 2; ++r2) acc[r2] = (floatx16)0.0f;
        const _Float16* wb = Wp + ((size_t)(kb * NLAY + l) * 16) * 2048;

        #pragma unroll
        for (int kk = 0; kk < 8; ++kk) {
            const _Float16* bp = wb + (size_t)(kk * 2 + hi) * 2048;
            half8 b_h = *(const half8*)(bp + wcol * 8);
            half8 b_l = *(const half8*)(bp + 1024 + wcol * 8);
            #pragma unroll
            for (int r2 = 0; r2 < 2; ++r2) {
                int rrow = (rh * 2 + r2) * 32 + lo;
                half8 a_h = *(const half8*)(Xhi + rrow * PX + kk * 16 + hi * 8);
                half8 a_l = *(const half8*)(Xlo + rrow * PX + kk * 16 + hi * 8);
                acc[r2] = __builtin_amdgcn_mfma_f32_32x32x16_f16(a_h, b_h, acc[r2], 0, 0, 0);
                acc[r2] = __builtin_amdgcn_mfma_f32_32x32x16_f16(a_h, b_l, acc[r2], 0, 0, 0);
                acc[r2] = __builtin_amdgcn_mfma_f32_32x32x16_f16(a_l, b_h, acc[r2], 0, 0, 0);
            }
        }
        __syncthreads();   // all waves' X reads for layer l done

        if (l < NLAY - 1) {
            // writeback: fixed column wcol, rows (rh*2+r2)*32+drow
            #pragma unroll
            for (int r2 = 0; r2 < 2; ++r2)
                #pragma unroll
                for (int reg = 0; reg < 16; ++reg) {
                    int n = (rh * 2 + r2) * 32 + drow_(reg, hi);
                    float vv = fmaxf(acc[r2][reg], 0.0f);
                    Xhi[n * PX + wcol] = hi_(vv);
                    Xlo[n * PX + wcol] = lo_(vv);
                }
        } else {
            // final layer: Xt[e][m]; lane's fixed dim IS e=wcol -> contiguous half4 in m
            #pragma unroll
            for (int r2 = 0; r2 < 2; ++r2)
                #pragma unroll
                for (int s = 0; s < 4; ++s) {
                    int m0 = (rh * 2 + r2) * 32 + 8 * s + 4 * hi;
                    half4 hh, ll;
                    #pragma unroll
                    for (int j = 0; j < 4; ++j) {
                        float vv = acc[r2][4 * s + j];
                        hh[j] = hi_(vv); ll[j] = lo_(vv);
                    }
                    *(half4*)(Xhi + wcol * PX + m0) = hh;
                    *(half4*)(Xlo + wcol * PX + m0) = ll;
                }
        }
        __syncthreads();
    }

    // ---- aggregation: m[n][d] = sum_m g[b,kb,n,m]*xb[m][d]; A = g (inline split), B = Xt ----
    const int rtw = wave & 3, ch = wave >> 2;
    const int row = rtw * 32 + lo;
    #pragma unroll
    for (int c2 = 0; c2 < 2; ++c2) acc[c2] = (floatx16)0.0f;
    const float* grow = gmat + (size_t)(b * NBOND + kb) * 16384;

    #pragma unroll 2
    for (int kk = 0; kk < 8; ++kk) {
        const float* gp = grow + (size_t)row * 128 + kk * 16 + hi * 8;
        float4 u = *(const float4*)gp, v2 = *(const float4*)(gp + 4);
        float av[8] = {u.x, u.y, u.z, u.w, v2.x, v2.y, v2.z, v2.w};
        half8 a_h, a_l;
        #pragma unroll
        for (int j = 0; j < 8; ++j) { a_h[j] = hi_(av[j]); a_l[j] = lo_(av[j]); }
        #pragma unroll
        for (int c2 = 0; c2 < 2; ++c2) {
            int ct = ch * 2 + c2;
            half8 b_h = *(const half8*)(Xhi + (ct * 32 + lo) * PX + kk * 16 + hi * 8);
            half8 b_l = *(const half8*)(Xlo + (ct * 32 + lo) * PX + kk * 16 + hi * 8);
            acc[c2] = __builtin_amdgcn_mfma_f32_32x32x16_f16(a_h, b_h, acc[c2], 0, 0, 0);
            acc[c2] = __builtin_amdgcn_mfma_f32_32x32x16_f16(a_h, b_l, acc[c2], 0, 0, 0);
            acc[c2] = __builtin_amdgcn_mfma_f32_32x32x16_f16(a_l, b_h, acc[c2], 0, 0, 0);
        }
    }

    if (kb == NBOND - 1) {
        #pragma unroll
        for (int c2 = 0; c2 < 2; ++c2)
            #pragma unroll
            for (int reg = 0; reg < 16; ++reg) {
                int n = rtw * 32 + drow_(reg, hi);
                m_uni[((size_t)(b * 128 + n)) * 128 + (ch * 2 + c2) * 32 + lo] = acc[c2][reg];
            }
    } else {
        #pragma unroll
        for (int c2 = 0; c2 < 2; ++c2)
            #pragma unroll
            for (int reg = 0; reg < 16; ++reg) {
                int n = rtw * 32 + drow_(reg, hi);
                atomicAdd(m_non + ((size_t)(b * 128 + n)) * 128 + (ch * 2 + c2) * 32 + lo,
                          acc[c2][reg]);
            }
    }
}

// ---------------------------------------------------------------- grouped GRU (split-fp16 MFMA)
// Dense grid of NDESC blocks; block -> (tt, slice) via desc with XCD-chunked
// mapping: XCD k (blocks with bid%8==k) owns desc[65k..65k+64], so same-type
// blocks (sharing 392 KB of GRU weights) cluster on one XCD's L2.
// One block = 32 gathered nodes of one type, BOTH GRU variants (v-loop, M
// restaged per v). LDS 35 KB -> up to 4 blocks/CU. Block owns its 32 nodes
// exclusively -> in-place update of hT: v=0 stores, v=1 read-add-stores.
__global__ __launch_bounds__(256, 3) void gru_mfma(
    float* __restrict__ hT,
    const float* __restrict__ m_non, const float* __restrict__ m_uni,
    const int* __restrict__ counts, const int* __restrict__ bucket,
    const int* __restrict__ desc,
    const _Float16* __restrict__ Wp, const float* __restrict__ bihp, const float* __restrict__ bhhp)
{
    __shared__ _Float16 Xh[32 * PX], Xl[32 * PX], Mh[32 * PX], Ml[32 * PX];
    __shared__ int bl[32];

    const int bid = blockIdx.x;
    const int dv = desc[(bid & 7) * (NDESC / 8) + (bid >> 3)];
    if (dv < 0) return;
    const int tt = dv & 7;
    const int base = (dv >> 3) * 32;
    const int t = threadIdx.x;
    const int cnt = counts[tt];
    const int nn = min(32, cnt - base);
    if (t < 32) bl[t] = (t < nn) ? bucket[tt * NNODES + base + t] : -1;
    __syncthreads();

    // stage X once (gathered h rows, split fp16, zero-fill inactive)
    for (int q = t; q < 32 * 32; q += 256) {
        int r = q >> 5, c4 = q & 31;
        float4 xv = make_float4(0.f, 0.f, 0.f, 0.f);
        int node = bl[r];
        if (node >= 0) xv = *(const float4*)(hT + (size_t)node * 128 + c4 * 4);
        half4 hh, ll;
        hh[0] = hi_(xv.x); ll[0] = lo_(xv.x);
        hh[1] = hi_(xv.y); ll[1] = lo_(xv.y);
        hh[2] = hi_(xv.z); ll[2] = lo_(xv.z);
        hh[3] = hi_(xv.w); ll[3] = lo_(xv.w);
        *(half4*)(Xh + r * PX + c4 * 4) = hh;
        *(half4*)(Xl + r * PX + c4 * 4) = ll;
    }

    const int wave = t >> 6, lane = t & 63, lo = lane & 31, hi = lane >> 5;
    const int d = wave * 32 + lo;

    #pragma unroll 1
    for (int v = 0; v < 2; ++v) {
        const float* msrc = v ? m_uni : m_non;
        __syncthreads();   // v=0: X-stage commit; v=1: prior M readers done
        for (int q = t; q < 32 * 32; q += 256) {
            int r = q >> 5, c4 = q & 31;
            float4 mv = make_float4(0.f, 0.f, 0.f, 0.f);
            int node = bl[r];
            if (node >= 0) mv = *(const float4*)(msrc + (size_t)node * 128 + c4 * 4);
            half4 hh, ll;
            hh[0] = hi_(mv.x); ll[0] = lo_(mv.x);
            hh[1] = hi_(mv.y); ll[1] = lo_(mv.y);
            hh[2] = hi_(mv.z); ll[2] = lo_(mv.z);
            hh[3] = hi_(mv.w); ll[3] = lo_(mv.w);
            *(half4*)(Mh + r * PX + c4 * 4) = hh;
            *(half4*)(Ml + r * PX + c4 * 4) = ll;
        }
        __syncthreads();

        const int vt = v * NTYPE + tt;
        const _Float16* pih = Wp + (size_t)(vt * 2 + 0) * 98304;
        const _Float16* phh = Wp + (size_t)(vt * 2 + 1) * 98304;

        floatx16 ar = (floatx16)0.0f, az = (floatx16)0.0f;
        floatx16 ax = (floatx16)0.0f, ah = (floatx16)0.0f;

        #pragma unroll 2
        for (int kk = 0; kk < 8; ++kk) {
            int koff = kk * 16 + hi * 8;
            half8 xh = *(const half8*)(Xh + lo * PX + koff);
            half8 xl = *(const half8*)(Xl + lo * PX + koff);
            half8 mh = *(const half8*)(Mh + lo * PX + koff);
            half8 ml = *(const half8*)(Ml + lo * PX + koff);
            const _Float16* ci = pih + (size_t)(kk * 2 + hi) * 6144;
            const _Float16* ch = phh + (size_t)(kk * 2 + hi) * 6144;
            half8 birh = *(const half8*)(ci + (0   + d) * 8);
            half8 birl = *(const half8*)(ci + 3072 + (0   + d) * 8);
            half8 bizh = *(const half8*)(ci + (128 + d) * 8);
            half8 bizl = *(const half8*)(ci + 3072 + (128 + d) * 8);
            half8 binh = *(const half8*)(ci + (256 + d) * 8);
            half8 binl = *(const half8*)(ci + 3072 + (256 + d) * 8);
            half8 bhrh = *(const half8*)(ch + (0   + d) * 8);
            half8 bhrl = *(const half8*)(ch + 3072 + (0   + d) * 8);
            half8 bhzh = *(const half8*)(ch + (128 + d) * 8);
            half8 bhzl = *(const half8*)(ch + 3072 + (128 + d) * 8);
            half8 bhnh = *(const half8*)(ch + (256 + d) * 8);
            half8 bhnl = *(const half8*)(ch + 3072 + (256 + d) * 8);

            ar = __builtin_amdgcn_mfma_f32_32x32x16_f16(xh, birh, ar, 0, 0, 0);
            ar = __builtin_amdgcn_mfma_f32_32x32x16_f16(xh, birl, ar, 0, 0, 0);
            ar = __builtin_amdgcn_mfma_f32_32x32x16_f16(xl, birh, ar, 0, 0, 0);
            ar = __builtin_amdgcn_mfma_f32_32x32x16_f16(mh, bhrh, ar, 0, 0, 0);
            ar = __builtin_amdgcn_mfma_f32_32x32x16_f16(mh, bhrl, ar, 0, 0, 0);
            ar = __builtin_amdgcn_mfma_f32_32x32x16_f16(ml, bhrh, ar, 0, 0, 0);

            az = __builtin_amdgcn_mfma_f32_32x32x16_f16(xh, bizh, az, 0, 0, 0);
            az = __builtin_amdgcn_mfma_f32_32x32x16_f16(xh, bizl, az, 0, 0, 0);
            az = __builtin_amdgcn_mfma_f32_32x32x16_f16(xl, bizh, az, 0, 0, 0);
            az = __builtin_amdgcn_mfma_f32_32x32x16_f16(mh, bhzh, az, 0, 0, 0);
            az = __builtin_amdgcn_mfma_f32_32x32x16_f16(mh, bhzl, az, 0, 0, 0);
            az = __builtin_amdgcn_mfma_f32_32x32x16_f16(ml, bhzh, az, 0, 0, 0);

            ax = __builtin_amdgcn_mfma_f32_32x32x16_f16(xh, binh, ax, 0, 0, 0);
            ax = __builtin_amdgcn_mfma_f32_32x32x16_f16(xh, binl, ax, 0, 0, 0);
            ax = __builtin_amdgcn_mfma_f32_32x32x16_f16(xl, binh, ax, 0, 0, 0);
            ah = __builtin_amdgcn_mfma_f32_32x32x16_f16(mh, bhnh, ah, 0, 0, 0);
            ah = __builtin_amdgcn_mfma_f32_32x32x16_f16(mh, bhnl, ah, 0, 0, 0);
            ah = __builtin_amdgcn_mfma_f32_32x32x16_f16(ml, bhnh, ah, 0, 0, 0);
        }

        const float* bi = bihp + (size_t)vt * 384;
        const float* bh = bhhp + (size_t)vt * 384;
        float b_r  = bi[d] + bh[d];
        float b_z  = bi[128 + d] + bh[128 + d];
        float b_in = bi[256 + d];
        float b_hn = bh[256 + d];
        #pragma unroll
        for (int reg = 0; reg < 16; ++reg) {
            int n = drow_(reg, hi);
            int node = bl[n];
            if (node < 0) continue;
            float r  = sig_(ar[reg] + b_r);
            float z  = sig_(az[reg] + b_z);
            float nv = tanhf(ax[reg] + b_in + r * (ah[reg] + b_hn));
            float mv = msrc[(size_t)node * 128 + d];   // fp32 m for z*m
            float val = (1.0f - z) * nv + z * mv;
            if (v == 0) hT[(size_t)node * 128 + d] = val;                       // overwrite old h
            else        hT[(size_t)node * 128 + d] += val;                      // block owns node
        }
    }
}

// ---------------------------------------------------------------- launch
extern "C" void kernel_launch(void* const* d_in, const int* in_sizes, int n_in,
                              void* d_out, int out_size, void* d_ws, size_t ws_size,
                              hipStream_t stream) {
    const float* g    = (const float*)d_in[0];
    const float* h    = (const float*)d_in[1];
    const float* msgW = (const float*)d_in[2];
    const float* Wih  = (const float*)d_in[3];
    const float* Whh  = (const float*)d_in[4];
    const float* bih  = (const float*)d_in[5];
    const float* bhh  = (const float*)d_in[6];
    float* hT = (float*)d_out;

    char* ws = (char*)d_ws;
    float* m_non = (float*)ws;                                   // 8 MB
    float* m_uni = m_non + (size_t)NNODES * 128;                 // 8 MB
    int* counts  = (int*)(ws + 2 * (size_t)NNODES * 128 * 4);
    int* bucket  = counts + 8;                                   // [6][16384]
    int* desc    = bucket + NTYPE * NNODES;                      // [520]
    _Float16* WpM = (_Float16*)(desc + NDESC);                   // 1,835,008 halves (3.67 MB)
    _Float16* WpG = WpM + (size_t)NBOND * NLAY * 16 * 2048;      // 2,359,296 halves (4.72 MB)

    (void)hipMemsetAsync(counts, 0, 8 * sizeof(int), stream);
    setup_kernel<<<NNODES * 128 / 256, 256, 0, stream>>>(h, hT, counts, bucket);
    build_desc_kernel<<<1, 64, 0, stream>>>(counts, desc);
    pack_msg_kernel<<<(NBOND * NLAY * 16 * 128 + 255) / 256, 256, 0, stream>>>(msgW, WpM);
    pack_gru_kernel<<<(2 * NTYPE * 2 * 16 * 384 + 255) / 256, 256, 0, stream>>>(Wih, Whh, WpG);

    for (int pass = 0; pass < 3; ++pass) {
        (void)hipMemsetAsync(m_non, 0, (size_t)NNODES * 128 * 4, stream);
        mlp_agg_mfma<<<dim3(NBOND, 128), 512, 0, stream>>>(hT, WpM, g, m_non, m_uni);
        gru_mfma<<<dim3(NDESC), 256, 0, stream>>>(hT, m_non, m_uni, counts, bucket, desc,
                                                  WpG, bih, bhh);
    }
}